// Round 3
// baseline (346.089 us; speedup 1.0000x reference)
//
#include <hip/hip_runtime.h>

// CoL: out[p] = sum_{q in 3x3} W[q-p] * L[bin(x_q), bin(x_p)] * x_q
// B=32 C=64 H=128 W=128, L is 5x5, zero pad, bin(x)=clamp((int)(x*5),0,4).
//
// R5 design (rolling-window walker + prefetch):
//  - 1 block per plane; thread = 8-col strip x 8-row walk (4 steps x 2 rows).
//  - 4-row x 10-col window rolls down: only 2 NEW rows loaded+quantized per
//    step (window reuse halves global loads and quant VALU vs R4).
//  - Cross-step prefetch: next 2 rows' loads are issued BEFORE computing the
//    current step -> HBM latency hides under 144 FMA + 144 ds_read gathers.
//    Waves live 4 steps and keep the LDS pipe continuously fed (R4 waves
//    were ~96% stalled: one exposed global wait per tiny block).
//  - bp4 (center bin*4) recomputed from bq20 via exact magic mul
//    ((b20*52429)>>18 == b*4 for b in 0..4) -> keeps VGPR below the
//    3-waves/SIMD cliff instead of storing 32 more ints.
//  - Plain stores (R4 nontemporal stores INCREASED write traffic 131->155MB).
//  - LDS table WL[9][25] = W*L fused; the 25 dwords of a sub-table land in 25
//    distinct banks (bq*5+bp in 0..24), same-address lanes broadcast ->
//    gathers are conflict-free by construction (measured 0 conflicts).

namespace {
constexpr int H  = 128;
constexpr int WD = 128;
constexpr int PLANES = 32 * 64;          // B*C = 2048 blocks (1 per plane)
constexpr int PX = 8;                    // pixels per row per thread
constexpr int STEPS = 4;                 // 2 rows per step -> 8 rows/thread
constexpr int THREADS = 256;             // 16 col-strips x 16 row-walkers
}

__global__ __launch_bounds__(THREADS, 3) void col_kernel(
    const float* __restrict__ x, const float* __restrict__ Wf,
    const float* __restrict__ Lf, float* __restrict__ out)
{
    __shared__ float WL[9 * 25];         // WL[(dr*3+dw)*25 + bq*5 + bp]
    const int t = threadIdx.x;
    if (t < 225) WL[t] = Wf[t / 25] * Lf[t % 25];
    __syncthreads();

    const int col0 = (t & 15) * PX;
    const int r0   = (t >> 4) * (2 * STEPS);     // first output row of walk

    const float* xp = x + (size_t)blockIdx.x * (H * WD);
    float* opb      = out + (size_t)blockIdx.x * (H * WD);

    // ---- helpers ------------------------------------------------------
    auto load_row = [&](int rr, float v[PX + 2]) {
        if (rr >= 0 && rr < H) {
            const float* rp = xp + rr * WD + col0;
            float4 c0 = *(const float4*)rp;          // 16B aligned
            float4 c1 = *(const float4*)(rp + 4);
            v[0] = (col0 > 0) ? rp[-1] : 0.f;
            v[1] = c0.x; v[2] = c0.y; v[3] = c0.z; v[4] = c0.w;
            v[5] = c1.x; v[6] = c1.y; v[7] = c1.z; v[8] = c1.w;
            v[9] = (col0 < WD - PX) ? rp[PX] : 0.f;
        } else {
            #pragma unroll
            for (int j = 0; j < PX + 2; ++j) v[j] = 0.f;
        }
    };
    auto quant_row = [&](const float v[PX + 2], int bq[PX + 2]) {
        #pragma unroll
        for (int j = 0; j < PX + 2; ++j) {
            int b = (int)(v[j] * 5.0f);              // x>=0: trunc==floor
            b = (b > 4) ? 4 : b;
            bq[j] = b * 20;                          // byte offset of L row
        }
    };

    // ---- prologue: window rows r0-1 .. r0+2 into phys slots 0..3 ------
    float win[4][PX + 2];
    int   bq20[4][PX + 2];
    #pragma unroll
    for (int k = 0; k < 4; ++k) {
        load_row(r0 - 1 + k, win[k]);
        quant_row(win[k], bq20[k]);
    }

    const char* wlb = (const char*)WL;

    // ---- 4 steps, window advances 2 rows per step ---------------------
    #pragma unroll
    for (int s = 0; s < STEPS; ++s) {
        // phys mapping: win[pa]=r-1, win[pb]=r, win[pc]=r+1, win[pd]=r+2
        const int pa = (s & 1) ? 2 : 0;
        const int pb = (s & 1) ? 3 : 1;
        const int pc = (s & 1) ? 0 : 2;
        const int pd = (s & 1) ? 1 : 3;
        const int r  = r0 + 2 * s;

        // prefetch next step's 2 rows (issued before compute; the wait
        // lands after the gather/FMA block -> HBM latency hidden)
        float nxt0[PX + 2], nxt1[PX + 2];
        if (s < STEPS - 1) {
            load_row(r + 3, nxt0);
            load_row(r + 4, nxt1);
        }

        // center-row bins as byte offsets: b*4 == (b*20 * 52429) >> 18
        int bp4a[PX], bp4b[PX];
        #pragma unroll
        for (int i = 0; i < PX; ++i) {
            bp4a[i] = (bq20[pb][i + 1] * 52429) >> 18;
            bp4b[i] = (bq20[pc][i + 1] * 52429) >> 18;
        }

        float acca[PX], accb[PX];
        #pragma unroll
        for (int i = 0; i < PX; ++i) { acca[i] = 0.f; accb[i] = 0.f; }

        const int R0[3] = {pa, pb, pc};              // q-rows for out row r
        const int R1[3] = {pb, pc, pd};              // q-rows for out row r+1

        #pragma unroll
        for (int dr = 0; dr < 3; ++dr) {
            #pragma unroll
            for (int dw = 0; dw < 3; ++dw) {
                const int imm = (dr * 3 + dw) * 100;
                float lwa[PX], lwb[PX];
                // 16 independent gathers issued before any consumer
                #pragma unroll
                for (int i = 0; i < PX; ++i)
                    lwa[i] = *(const float*)(
                        wlb + (bq20[R0[dr]][i + dw] + bp4a[i] + imm));
                #pragma unroll
                for (int i = 0; i < PX; ++i)
                    lwb[i] = *(const float*)(
                        wlb + (bq20[R1[dr]][i + dw] + bp4b[i] + imm));
                #pragma unroll
                for (int i = 0; i < PX; ++i)
                    acca[i] = fmaf(lwa[i], win[R0[dr]][i + dw], acca[i]);
                #pragma unroll
                for (int i = 0; i < PX; ++i)
                    accb[i] = fmaf(lwb[i], win[R1[dr]][i + dw], accb[i]);
            }
        }

        float* op = opb + r * WD + col0;
        *(float4*)op            = make_float4(acca[0], acca[1], acca[2], acca[3]);
        *(float4*)(op + 4)      = make_float4(acca[4], acca[5], acca[6], acca[7]);
        *(float4*)(op + WD)     = make_float4(accb[0], accb[1], accb[2], accb[3]);
        *(float4*)(op + WD + 4) = make_float4(accb[4], accb[5], accb[6], accb[7]);

        // retire prefetched rows into the freed window slots (pa, pb)
        if (s < STEPS - 1) {
            #pragma unroll
            for (int j = 0; j < PX + 2; ++j) win[pa][j] = nxt0[j];
            quant_row(win[pa], bq20[pa]);
            #pragma unroll
            for (int j = 0; j < PX + 2; ++j) win[pb][j] = nxt1[j];
            quant_row(win[pb], bq20[pb]);
        }
    }
}

extern "C" void kernel_launch(void* const* d_in, const int* in_sizes, int n_in,
                              void* d_out, int out_size, void* d_ws, size_t ws_size,
                              hipStream_t stream) {
    const float* x  = (const float*)d_in[0];   // input_tensor (B,C,H,W) fp32
    const float* Wf = (const float*)d_in[1];   // W (1,3,3) fp32
    const float* Lf = (const float*)d_in[2];   // L (5,5) fp32
    float* out = (float*)d_out;

    col_kernel<<<dim3(PLANES), dim3(THREADS), 0, stream>>>(x, Wf, Lf, out);
}

// Round 5
// 252.201 us; speedup vs baseline: 1.3723x; 1.3723x over previous
//
#include <hip/hip_runtime.h>

// CoL: out[p] = sum_{q in 3x3} W[q-p] * L[bin(x_q), bin(x_p)] * x_q
// B=32 C=64 H=128 W=128, L is 5x5, zero pad, bin(x)=clamp((int)(x*5),0,4).
//
// R7 = R6 resubmitted verbatim (R6 bench was an infra failure: container
// died twice, no compile/run evidence).
//
// R6 = R5 concept (long-lived walker blocks + rolling window + cross-step
// prefetch), scratch-proofed. R5 put win/bq in scratch (WRITE 339MB vs
// 134MB output, VALUBusy 12%) because of runtime slot indices + lambdas
// taking array pointers. Here every array index is a LITERAL: the 4 walk
// steps are written out with macro-expanded constant slot rotation
// (0123 / 2301 / 0123 / 2301), loads/quant/retire are macros, no lambdas,
// no index arrays.
//
//  - 1 block per plane (2048 blocks); thread = 8-col strip x 8-row walk
//    (4 steps x 2 rows). Blocks live the whole kernel -> no CP dispatch
//    bottleneck, stalls amortized over 4 steps.
//  - Rolling 4-row x 10-col window: 2 NEW rows loaded+quantized per step.
//  - Prefetch: next step's 2 rows issued BEFORE current step's 144
//    gather+fma -> HBM latency hidden under compute.
//  - bp4 from bq20 via exact magic mul ((b20*52429)>>18 == b*4, b in 0..4).
//  - Plain float4 stores (R4 nontemporal stores raised WRITE 131->155MB).
//  - LDS table WL[9][25] = W*L; each 25-dword sub-table spans 25 distinct
//    banks, same-address lanes broadcast -> conflict-free (measured 0).

namespace {
constexpr int H  = 128;
constexpr int WD = 128;
constexpr int PLANES = 32 * 64;          // B*C = 2048 blocks (1 per plane)
constexpr int PX = 8;                    // pixels per row per thread
constexpr int THREADS = 256;             // 16 col-strips x 16 row-walkers
}

__global__ __launch_bounds__(THREADS, 2) void col_kernel(
    const float* __restrict__ x, const float* __restrict__ Wf,
    const float* __restrict__ Lf, float* __restrict__ out)
{
    __shared__ float WL[9 * 25];         // WL[(dr*3+dw)*25 + bq*5 + bp]
    const int t = threadIdx.x;
    if (t < 225) WL[t] = Wf[t / 25] * Lf[t % 25];
    __syncthreads();

    const int col0 = (t & 15) * PX;
    const int r0   = (t >> 4) * 8;       // first output row of this walker

    const float* xp = x + (size_t)blockIdx.x * (H * WD);
    float* opb      = out + (size_t)blockIdx.x * (H * WD);
    const char* wlb = (const char*)WL;

    float win[4][PX + 2];
    int   bq[4][PX + 2];                 // bin*20 (byte offset of L row)
    float n0[PX + 2], n1[PX + 2];        // prefetch buffers

// ---- all-literal-index helpers (no lambdas: keep mem2reg alive) --------
#define LOAD_ROW(DST, RR) {                                               \
    const int _rr = (RR);                                                 \
    if (_rr >= 0 && _rr < H) {                                            \
        const float* _rp = xp + _rr * WD + col0;                          \
        const float4 _c0 = *(const float4*)_rp;      /* 16B aligned */    \
        const float4 _c1 = *(const float4*)(_rp + 4);                     \
        DST[0] = (col0 > 0) ? _rp[-1] : 0.f;                              \
        DST[1] = _c0.x; DST[2] = _c0.y; DST[3] = _c0.z; DST[4] = _c0.w;   \
        DST[5] = _c1.x; DST[6] = _c1.y; DST[7] = _c1.z; DST[8] = _c1.w;   \
        DST[9] = (col0 < WD - PX) ? _rp[PX] : 0.f;                        \
    } else {                                                              \
        _Pragma("unroll")                                                 \
        for (int _j = 0; _j < PX + 2; ++_j) DST[_j] = 0.f;                \
    } }

#define QUANT_ROW(S) {                                                    \
    _Pragma("unroll")                                                     \
    for (int _j = 0; _j < PX + 2; ++_j) {                                 \
        int _b = (int)(win[S][_j] * 5.0f);    /* x>=0: trunc==floor */    \
        _b = (_b > 4) ? 4 : _b;                                           \
        bq[S][_j] = _b * 20;                                              \
    } }

#define RETIRE(S, SRC) {                                                  \
    _Pragma("unroll")                                                     \
    for (int _j = 0; _j < PX + 2; ++_j) win[S][_j] = SRC[_j];             \
    QUANT_ROW(S) }

// 24 gathers + 24 fma for one q-row (slot QS) at window row DR into ACC.
#define TERMS(QS, DR, BP, ACC) {                                          \
    _Pragma("unroll")                                                     \
    for (int _dw = 0; _dw < 3; ++_dw) {                                   \
        float _lw[PX];                                                    \
        _Pragma("unroll")                                                 \
        for (int _i = 0; _i < PX; ++_i)                                   \
            _lw[_i] = *(const float*)(wlb +                               \
                (bq[QS][_i + _dw] + BP[_i] + ((DR) * 3 + _dw) * 100));    \
        _Pragma("unroll")                                                 \
        for (int _i = 0; _i < PX; ++_i)                                   \
            ACC[_i] = fmaf(_lw[_i], win[QS][_i + _dw], ACC[_i]);          \
    } }

// Compute+store output rows R (center slot PB) and R+1 (center slot PC);
// window slots PA..PD hold rows R-1, R, R+1, R+2.
#define COMPUTE2(PA, PB, PC, PD, R) {                                     \
    int bp4a[PX], bp4b[PX];                                               \
    _Pragma("unroll")                                                     \
    for (int _i = 0; _i < PX; ++_i) {                                     \
        bp4a[_i] = (bq[PB][_i + 1] * 52429) >> 18;   /* b*20 -> b*4 */    \
        bp4b[_i] = (bq[PC][_i + 1] * 52429) >> 18;                        \
    }                                                                     \
    float acca[PX], accb[PX];                                             \
    _Pragma("unroll")                                                     \
    for (int _i = 0; _i < PX; ++_i) { acca[_i] = 0.f; accb[_i] = 0.f; }   \
    TERMS(PA, 0, bp4a, acca)                                              \
    TERMS(PB, 0, bp4b, accb)                                              \
    TERMS(PB, 1, bp4a, acca)                                              \
    TERMS(PC, 1, bp4b, accb)                                              \
    TERMS(PC, 2, bp4a, acca)                                              \
    TERMS(PD, 2, bp4b, accb)                                              \
    float* _op = opb + (R) * WD + col0;                                   \
    *(float4*)_op            = make_float4(acca[0], acca[1], acca[2], acca[3]); \
    *(float4*)(_op + 4)      = make_float4(acca[4], acca[5], acca[6], acca[7]); \
    *(float4*)(_op + WD)     = make_float4(accb[0], accb[1], accb[2], accb[3]); \
    *(float4*)(_op + WD + 4) = make_float4(accb[4], accb[5], accb[6], accb[7]); \
    }

    // ---- prologue: rows r0-1 .. r0+2 into slots 0..3 ------------------
    LOAD_ROW(win[0], r0 - 1) QUANT_ROW(0)
    LOAD_ROW(win[1], r0 + 0) QUANT_ROW(1)
    LOAD_ROW(win[2], r0 + 1) QUANT_ROW(2)
    LOAD_ROW(win[3], r0 + 2) QUANT_ROW(3)

    // ---- step 0: rows r0, r0+1 ----------------------------------------
    LOAD_ROW(n0, r0 + 3)                 // prefetch (consumed after compute)
    LOAD_ROW(n1, r0 + 4)
    COMPUTE2(0, 1, 2, 3, r0)
    RETIRE(0, n0) RETIRE(1, n1)

    // ---- step 1: rows r0+2, r0+3 --------------------------------------
    LOAD_ROW(n0, r0 + 5)
    LOAD_ROW(n1, r0 + 6)
    COMPUTE2(2, 3, 0, 1, r0 + 2)
    RETIRE(2, n0) RETIRE(3, n1)

    // ---- step 2: rows r0+4, r0+5 --------------------------------------
    LOAD_ROW(n0, r0 + 7)
    LOAD_ROW(n1, r0 + 8)
    COMPUTE2(0, 1, 2, 3, r0 + 4)
    RETIRE(0, n0) RETIRE(1, n1)

    // ---- step 3: rows r0+6, r0+7 --------------------------------------
    COMPUTE2(2, 3, 0, 1, r0 + 6)

#undef LOAD_ROW
#undef QUANT_ROW
#undef RETIRE
#undef TERMS
#undef COMPUTE2
}

extern "C" void kernel_launch(void* const* d_in, const int* in_sizes, int n_in,
                              void* d_out, int out_size, void* d_ws, size_t ws_size,
                              hipStream_t stream) {
    const float* x  = (const float*)d_in[0];   // input_tensor (B,C,H,W) fp32
    const float* Wf = (const float*)d_in[1];   // W (1,3,3) fp32
    const float* Lf = (const float*)d_in[2];   // L (5,5) fp32
    float* out = (float*)d_out;

    col_kernel<<<dim3(PLANES), dim3(THREADS), 0, stream>>>(x, Wf, Lf, out);
}